// Round 5
// baseline (1297.509 us; speedup 1.0000x reference)
//
#include <hip/hip_runtime.h>
#include <hip/hip_fp16.h>

typedef unsigned short u16;
typedef short bf16x8 __attribute__((ext_vector_type(8)));
typedef _Float16 half8 __attribute__((ext_vector_type(8)));
typedef float f32x4 __attribute__((ext_vector_type(4)));

__device__ __forceinline__ u16 f2bf(float f) {
    unsigned u = __float_as_uint(f);
    return (u16)((u + 0x7fffu + ((u >> 16) & 1u)) >> 16);
}
__device__ __forceinline__ u16 f2h(float f) {
    __half h = __float2half_rn(f);
    return *reinterpret_cast<u16*>(&h);
}

// ---- async global->LDS, width 16B per lane, dest = wave base + lane*16 ----
__device__ __forceinline__ void gload_lds16(const void* g, void* l) {
    __builtin_amdgcn_global_load_lds(
        (const __attribute__((address_space(1))) unsigned int*)g,
        (__attribute__((address_space(3))) unsigned int*)l, 16, 0, 0);
}

// =====================================================================
// Bitmask + init of the per-layer f2-max atomic slots
__global__ __launch_bounds__(256) void k_mask(const float* __restrict__ adj,
                                              unsigned* __restrict__ mask,
                                              int* __restrict__ slots) {
    int w = blockIdx.x * 256 + threadIdx.x;
    const float4* q = (const float4*)(adj + (size_t)w * 32);
    unsigned bits = 0u;
#pragma unroll
    for (int i = 0; i < 8; i++) {
        float4 v = q[i];
        if (v.x > 0.f) bits |= (1u << (i * 4 + 0));
        if (v.y > 0.f) bits |= (1u << (i * 4 + 1));
        if (v.z > 0.f) bits |= (1u << (i * 4 + 2));
        if (v.w > 0.f) bits |= (1u << (i * 4 + 3));
    }
    mask[w] = bits;
    if (blockIdx.x == 0 && threadIdx.x < 64) slots[threadIdx.x] = (int)0x80000000;
}

// =====================================================================
__global__ void k_trans(const float* __restrict__ in, u16* __restrict__ out, int K) {
    __shared__ float t[32][33];
    const float* src = in + (size_t)blockIdx.z * K * 128;
    u16* dst = out + (size_t)blockIdx.z * K * 128;
    int k0 = blockIdx.x * 32, n0 = blockIdx.y * 32;
    int tx = threadIdx.x, ty = threadIdx.y;
#pragma unroll
    for (int i = 0; i < 32; i += 8) t[ty + i][tx] = src[(size_t)(k0 + ty + i) * 128 + n0 + tx];
    __syncthreads();
#pragma unroll
    for (int i = 0; i < 32; i += 8) dst[(size_t)(n0 + ty + i) * K + k0 + tx] = f2bf(t[tx][ty + i]);
}

// =====================================================================
__global__ __launch_bounds__(256) void k_cvt(const float* __restrict__ in,
                                             u16* __restrict__ out) {
    int t = blockIdx.x * 256 + threadIdx.x;
    float4 v = ((const float4*)in)[t];
    uint2 o;
    o.x = (unsigned)f2bf(v.x) | ((unsigned)f2bf(v.y) << 16);
    o.y = (unsigned)f2bf(v.z) | ((unsigned)f2bf(v.w) << 16);
    ((uint2*)out)[t] = o;
}

// =====================================================================
// Projection. X bf16, WT bf16 [n][k]. Writes WhT[n][j] as F16, f1 fp32,
// E12 = {2^f2', 2^0.2f2'} fp32, and atomicMax of f2' into fsl[h].
__global__ __launch_bounds__(1024, 4) void k_proj(const u16* __restrict__ X,
                                                  const u16* __restrict__ WT,
                                                  const float* __restrict__ avec,
                                                  u16* __restrict__ WhT,
                                                  float* __restrict__ f1,
                                                  float* __restrict__ E12g,
                                                  int* __restrict__ fsl, int Fin) {
    __shared__ u16 As[2][64 * 32];
    __shared__ u16 Bs[2][128 * 32];
    __shared__ float fpart[4][64][2];
    const int tid = threadIdx.x;
    const int wv = tid >> 6, lane = tid & 63;
    const int rg = wv & 3, cg = wv >> 2;
    const int c = lane & 15, quad = lane >> 4;
    const int bofs = (quad ^ ((c >> 1) & 3)) * 8;
    const int h = blockIdx.y;
    const int j0 = blockIdx.x * 64;
    const u16* Wp = WT + (size_t)h * 128 * Fin;
    const int sgr = ((lane & 3) ^ ((lane >> 3) & 3)) * 8;

#define PROJ_STAGE(buf, kb)                                                              \
    do {                                                                                 \
        if (cg == 0)                                                                     \
            gload_lds16(X + (size_t)(j0 + rg * 16 + (lane >> 2)) * Fin + (kb) + sgr,     \
                        (void*)&As[buf][rg * 16 * 32]);                                  \
        else if (cg <= 2)                                                                \
            gload_lds16(Wp + (size_t)((cg - 1) * 64 + rg * 16 + (lane >> 2)) * Fin + (kb) + sgr, \
                        (void*)&Bs[buf][((cg - 1) * 64 + rg * 16) * 32]);                \
    } while (0)

    PROJ_STAGE(0, 0);
    __syncthreads();

    f32x4 acc[2];
    acc[0] = (f32x4){0.f, 0.f, 0.f, 0.f};
    acc[1] = (f32x4){0.f, 0.f, 0.f, 0.f};

    int it = 0;
    for (int kb = 0; kb < Fin; kb += 32, it++) {
        const int cur = it & 1;
        if (kb + 32 < Fin) PROJ_STAGE(cur ^ 1, kb + 32);
        bf16x8 av = *(const bf16x8*)&As[cur][(rg * 16 + c) * 32 + bofs];
#pragma unroll
        for (int e = 0; e < 2; e++) {
            bf16x8 bv = *(const bf16x8*)&Bs[cur][((cg * 2 + e) * 16 + c) * 32 + bofs];
            acc[e] = __builtin_amdgcn_mfma_f32_16x16x32_bf16(av, bv, acc[e], 0, 0, 0);
        }
        __syncthreads();
    }

    u16* Wo = WhT + (size_t)h * 128 * 4096;
    const float* ah = avec + h * 256;
    float p1[4] = {0, 0, 0, 0}, p2[4] = {0, 0, 0, 0};
#pragma unroll
    for (int e = 0; e < 2; e++) {
        const int n = (cg * 2 + e) * 16 + c;
        float a1 = ah[n];
        float a2 = ah[128 + n];
        u16 w4[4];
#pragma unroll
        for (int r = 0; r < 4; r++) {
            float v = acc[e][r];
            w4[r] = f2h(v);                      // f16 output
            p1[r] += v * a1;
            p2[r] += v * a2;
        }
        uint2 pk;
        pk.x = (unsigned)w4[0] | ((unsigned)w4[1] << 16);
        pk.y = (unsigned)w4[2] | ((unsigned)w4[3] << 16);
        *(uint2*)&Wo[(size_t)n * 4096 + j0 + rg * 16 + quad * 4] = pk;
    }
#pragma unroll
    for (int off = 1; off < 16; off <<= 1) {
#pragma unroll
        for (int r = 0; r < 4; r++) {
            p1[r] += __shfl_xor(p1[r], off);
            p2[r] += __shfl_xor(p2[r], off);
        }
    }
    if (c == 0) {
#pragma unroll
        for (int r = 0; r < 4; r++) {
            fpart[cg][rg * 16 + quad * 4 + r][0] = p1[r];
            fpart[cg][rg * 16 + quad * 4 + r][1] = p2[r];
        }
    }
    __syncthreads();
    if (tid < 64) {
        float s1 = fpart[0][tid][0] + fpart[1][tid][0] + fpart[2][tid][0] + fpart[3][tid][0];
        float s2 = fpart[0][tid][1] + fpart[1][tid][1] + fpart[2][tid][1] + fpart[3][tid][1];
        f1[h * 4096 + j0 + tid] = s1;
        const float LOG2E = 1.4426950408889634f;
        float d = s2 * LOG2E;
        float* e12 = E12g + h * 8192 + 2 * (j0 + tid);
        e12[0] = __builtin_amdgcn_exp2f(d);
        e12[1] = __builtin_amdgcn_exp2f(0.2f * d);
        float dm = d;
#pragma unroll
        for (int off = 1; off < 64; off <<= 1) dm = fmaxf(dm, __shfl_xor(dm, off));
        if (tid == 0) {
            int b = __float_as_int(dm);
            atomicMax(fsl + h, b >= 0 ? b : (b ^ 0x7fffffff));
        }
    }
}

// =====================================================================
// Fused masked softmax attention + ELU — BARRIER-FREE k-loop.
// 512 thr = 8 waves; block = 64 i-rows x 4096 j. Wave w owns a PRIVATE
// 512-j chunk and 4 A-fragments (64 rows). Double-buffered private tile,
// counted s_waitcnt vmcnt(8) per iter (stage k+1 stays in flight), no
// __syncthreads until the final cross-wave reduction.
// P in packed f16: p = max(C1*E1, C2*E2) (exp select == max in 2^ domain).
// j-blocks permuted (quad q <-> block 16q+k) so masks preload as uint4.
template <bool F32OUT>
__global__ __launch_bounds__(512, 2) void k_attn(const u16* __restrict__ WhT,
                                                 const float* __restrict__ f1g,
                                                 const float* __restrict__ E12g,
                                                 const unsigned char* __restrict__ maskb,
                                                 const int* __restrict__ fmx,
                                                 void* __restrict__ outp, int ostride) {
    __shared__ u16 Bs[8][2][128 * 32];     // 128 KB; reused as red[] after loop
    __shared__ unsigned EL[4096 + 8];      // 16 KB packed f16x2 {E1,E2} per j
    __shared__ float lpart[8][64];

    const int tid = threadIdx.x;
    const int w = tid >> 6, lane = tid & 63;
    const int c = lane & 15, quad = lane >> 4;
    const int bofs = (quad ^ ((c >> 1) & 3)) * 8;
    const int g2 = (lane & 3) ^ ((lane >> 3) & 3);

    int h, ib;
    if (!F32OUT) {  // XCD-cluster: 2 XCDs per head (bid%8 ~ XCD)
        int bid = blockIdx.x + (blockIdx.y << 6);
        int xcd = bid & 7;
        h = xcd >> 1;
        ib = (bid >> 3) + ((xcd & 1) << 5);
    } else { h = 0; ib = blockIdx.x; }
    const int i0 = ib * 64;
    const float LOG2E = 1.4426950408889634f;
    const u16* Wp = WhT + (size_t)h * 128 * 4096;

    // ---- stage tile 0 (j-blocks 16*g2 + 0) ----
    const u16* sbase = Wp + (size_t)(lane >> 2) * 4096 + w * 512 + g2 * 128;
#pragma unroll
    for (int e8 = 0; e8 < 8; e8++)
        gload_lds16(sbase + (size_t)e8 * 16 * 4096, (void*)&Bs[w][0][e8 * 16 * 32]);
    const u16* sp = sbase + 8;

    // ---- F2MAX + per-wave E fill (own 512-j chunk; no barrier needed) ----
    int fk = fmx[h];
    float F2MAX = __int_as_float(fk >= 0 ? fk : (fk ^ 0x7fffffff));
    float t1 = __builtin_amdgcn_exp2f(-F2MAX);
    float t2 = __builtin_amdgcn_exp2f(-0.2f * F2MAX);
    {
        int j = w * 512 + lane * 8;
        const float4* eg = (const float4*)(E12g + h * 8192 + 2 * j);
#pragma unroll
        for (int m = 0; m < 4; m++) {
            float4 v = eg[m];
            __half2 p0 = __floats2half2_rn(v.x * t1, v.y * t2);
            __half2 p1 = __floats2half2_rn(v.z * t1, v.w * t2);
            EL[j + 2 * m] = *(const unsigned*)&p0;
            EL[j + 2 * m + 1] = *(const unsigned*)&p1;
        }
    }

    // ---- masks: 4 frag-rows x uint4 (16 iters of bytes, contiguous by perm) ----
    const unsigned char* mb0 = maskb + (size_t)(i0 + c) * 512 + w * 64 + quad * 16;
    uint4 mqa = *(const uint4*)(mb0);
    uint4 mqb = *(const uint4*)(mb0 + 16 * 512);
    uint4 mqc = *(const uint4*)(mb0 + 32 * 512);
    uint4 mqd = *(const uint4*)(mb0 + 48 * 512);
    unsigned cur0 = mqa.x, s10 = mqa.y, s20 = mqa.z, s30 = mqa.w;
    unsigned cur1 = mqb.x, s11 = mqb.y, s21 = mqb.z, s31 = mqb.w;
    unsigned cur2 = mqc.x, s12 = mqc.y, s22 = mqc.z, s32 = mqc.w;
    unsigned cur3 = mqd.x, s13 = mqd.y, s23 = mqd.z, s33 = mqd.w;

    // ---- per-frag constants {C1,C2} f16x2 ----
    __half2 cp0, cp1, cp2, cp3;
#define MKCP(dst, F)                                                                     \
    do {                                                                                 \
        float rf1 = f1g[h * 4096 + i0 + (F) * 16 + c] * LOG2E;                           \
        float zbv = rf1 + F2MAX;                                                         \
        float rmv = fmaxf(zbv, 0.2f * zbv);                                              \
        dst = __floats2half2_rn(__builtin_amdgcn_exp2f(zbv - rmv),                       \
                                __builtin_amdgcn_exp2f(0.2f * zbv - rmv));               \
    } while (0)
    MKCP(cp0, 0); MKCP(cp1, 1); MKCP(cp2, 2); MKCP(cp3, 3);

    half8 ones;
#pragma unroll
    for (int i = 0; i < 8; i++) ones[i] = (_Float16)1.0f;

    f32x4 acc0[8], acc1[8], acc2[8], acc3[8];
#pragma unroll
    for (int i = 0; i < 8; i++) {
        acc0[i] = (f32x4){0.f, 0.f, 0.f, 0.f};
        acc1[i] = (f32x4){0.f, 0.f, 0.f, 0.f};
        acc2[i] = (f32x4){0.f, 0.f, 0.f, 0.f};
        acc3[i] = (f32x4){0.f, 0.f, 0.f, 0.f};
    }
    f32x4 al0 = (f32x4){0.f, 0.f, 0.f, 0.f}, al1 = al0, al2 = al0, al3 = al0;

    int eoff = w * 512 + quad * 128;
    uint4 epA0 = *(const uint4*)&EL[eoff];
    uint4 epA1 = *(const uint4*)&EL[eoff + 4];
    uint4 epB0, epB1;
    eoff += 8;

    asm volatile("s_waitcnt vmcnt(0)" ::: "memory");   // drain prologue once
    __builtin_amdgcn_sched_barrier(0);

#define COMPF(dst, curw, cpf, U)                                                         \
    do {                                                                                 \
        const unsigned mbv = ((curw) >> (8 * (U))) & 0xffu;                              \
        _Pragma("unroll")                                                                \
        for (int t = 0; t < 4; t++) {                                                    \
            __half2 e0 = *(const __half2*)&ed[2 * t];                                    \
            __half2 e1 = *(const __half2*)&ed[2 * t + 1];                                \
            __half2 pr0 = __hmul2(e0, (cpf));                                            \
            __half2 pr1 = __hmul2(e1, (cpf));                                            \
            __half m0 = __hmax(__low2half(pr0), __high2half(pr0));                       \
            __half m1 = __hmax(__low2half(pr1), __high2half(pr1));                       \
            __half2 pk2 = __halves2half2(m0, m1);                                        \
            unsigned msk = (((mbv >> (2 * t)) & 1u) ? 0xffffu : 0u) |                    \
                           (((mbv >> (2 * t + 1)) & 1u) ? 0xffff0000u : 0u);             \
            dst.u[t] = (*(const unsigned*)&pk2) & msk;                                   \
        }                                                                                \
    } while (0)

#define BODY(U, BUF, NBUF, EC0, EC1, EN0, EN1)                                           \
    do {                                                                                 \
        _Pragma("unroll")                                                                \
        for (int e8 = 0; e8 < 8; e8++)                                                   \
            gload_lds16(sp + (size_t)e8 * 16 * 4096, (void*)&Bs[w][NBUF][e8 * 16 * 32]); \
        sp += 8;                                                                         \
        asm volatile("s_waitcnt vmcnt(8)" ::: "memory");                                 \
        __builtin_amdgcn_sched_barrier(0);                                               \
        EN0 = *(const uint4*)&EL[eoff];                                                  \
        EN1 = *(const uint4*)&EL[eoff + 4];                                              \
        eoff += 8;                                                                       \
        const unsigned ed[8] = {EC0.x, EC0.y, EC0.z, EC0.w, EC1.x, EC1.y, EC1.z, EC1.w}; \
        union AF { half8 v; unsigned u[4]; } af0, af1, af2, af3;                         \
        COMPF(af0, cur0, cp0, U);                                                        \
        COMPF(af1, cur1, cp1, U);                                                        \
        COMPF(af2, cur2, cp2, U);                                                        \
        COMPF(af3, cur3, cp3, U);                                                        \
        _Pragma("unroll")                                                                \
        for (int nt = 0; nt < 8; nt++) {                                                 \
            half8 bv = *(const half8*)&Bs[w][BUF][(nt * 16 + c) * 32 + bofs];            \
            acc0[nt] = __builtin_amdgcn_mfma_f32_16x16x32_f16(af0.v, bv, acc0[nt], 0, 0, 0); \
            acc1[nt] = __builtin_amdgcn_mfma_f32_16x16x32_f16(af1.v, bv, acc1[nt], 0, 0, 0); \
            acc2[nt] = __builtin_amdgcn_mfma_f32_16x16x32_f16(af2.v, bv, acc2[nt], 0, 0, 0); \
            acc3[nt] = __builtin_amdgcn_mfma_f32_16x16x32_f16(af3.v, bv, acc3[nt], 0, 0, 0); \
        }                                                                                \
        al0 = __builtin_amdgcn_mfma_f32_16x16x32_f16(af0.v, ones, al0, 0, 0, 0);         \
        al1 = __builtin_amdgcn_mfma_f32_16x16x32_f16(af1.v, ones, al1, 0, 0, 0);         \
        al2 = __builtin_amdgcn_mfma_f32_16x16x32_f16(af2.v, ones, al2, 0, 0, 0);         \
        al3 = __builtin_amdgcn_mfma_f32_16x16x32_f16(af3.v, ones, al3, 0, 0, 0);         \
    } while (0)

    for (int s = 0; s < 4; s++) {
        BODY(0, 0, 1, epA0, epA1, epB0, epB1);
        BODY(1, 1, 0, epB0, epB1, epA0, epA1);
        BODY(2, 0, 1, epA0, epA1, epB0, epB1);
        BODY(3, 1, 0, epB0, epB1, epA0, epA1);
        cur0 = s10; s10 = s20; s20 = s30;
        cur1 = s11; s11 = s21; s21 = s31;
        cur2 = s12; s12 = s22; s22 = s32;
        cur3 = s13; s13 = s23; s23 = s33;
    }

    // ---- row denominators from ones-MFMA ----
    if (c == 0) {
#pragma unroll
        for (int r = 0; r < 4; r++) {
            lpart[w][0 * 16 + quad * 4 + r] = al0[r];
            lpart[w][1 * 16 + quad * 4 + r] = al1[r];
            lpart[w][2 * 16 + quad * 4 + r] = al2[r];
            lpart[w][3 * 16 + quad * 4 + r] = al3[r];
        }
    }
    __syncthreads();       // all waves done with Bs; drain DMA

    // ---- cross-wave reduction in 4 quarter-buffers aliased onto Bs ----
    float* redb = (float*)&Bs[0][0][0];   // 32768 floats = 4 x [64][128]
#define DUMPQ(A, F)                                                                      \
    _Pragma("unroll") for (int nt = 0; nt < 8; nt++)                                     \
    _Pragma("unroll") for (int r = 0; r < 4; r++)                                        \
        rq[((F) * 16 + quad * 4 + r) * 128 + nt * 16 + c] = A[nt][r];
#define ADDQ(A, F)                                                                       \
    _Pragma("unroll") for (int nt = 0; nt < 8; nt++)                                     \
    _Pragma("unroll") for (int r = 0; r < 4; r++)                                        \
        rq[((F) * 16 + quad * 4 + r) * 128 + nt * 16 + c] += A[nt][r];
    if (w >= 4) {
        float* rq = redb + (w - 4) * 8192;
        DUMPQ(acc0, 0) DUMPQ(acc1, 1) DUMPQ(acc2, 2) DUMPQ(acc3, 3)
    }
    __syncthreads();
    if (w < 4) {
        float* rq = redb + w * 8192;
        ADDQ(acc0, 0) ADDQ(acc1, 1) ADDQ(acc2, 2) ADDQ(acc3, 3)
    }
    __syncthreads();
    {   // red0 += red2 ; red1 += red3 (all threads)
        f32x4* r0 = (f32x4*)redb;
        f32x4* r1 = (f32x4*)(redb + 8192);
        f32x4* r2 = (f32x4*)(redb + 16384);
        f32x4* r3 = (f32x4*)(redb + 24576);
        for (int t = tid; t < 2048; t += 512) { r0[t] += r2[t]; r1[t] += r3[t]; }
    }
    __syncthreads();

    // ---- epilogue: row = tid>>3 (64 rows), octets ob and ob+8 ----
    const int row = tid >> 3, ob = tid & 7;
    float l = 0.f;
#pragma unroll
    for (int g = 0; g < 8; g++) l += lpart[g][row];
    const float linv = 1.0f / l;
    float vv[16];
#pragma unroll
    for (int half = 0; half < 2; half++) {
#pragma unroll
        for (int t = 0; t < 8; t++) {
            int idx = row * 128 + (ob + half * 8) * 8 + t;
            float v = (redb[idx] + redb[8192 + idx]) * linv;
            vv[half * 8 + t] = v > 0.f ? v : __expf(v) - 1.f;   // ELU
        }
    }
    const size_t obase = (size_t)(i0 + row) * ostride + h * 128 + ob * 8;
    if (F32OUT) {
        float* op = (float*)outp + obase;
        *(float4*)op = *(float4*)&vv[0];
        *(float4*)(op + 4) = *(float4*)&vv[4];
        *(float4*)(op + 64) = *(float4*)&vv[8];
        *(float4*)(op + 68) = *(float4*)&vv[12];
    } else {
        u16* op = (u16*)outp + obase;
        uint4 o;
        o.x = (unsigned)f2bf(vv[0]) | ((unsigned)f2bf(vv[1]) << 16);
        o.y = (unsigned)f2bf(vv[2]) | ((unsigned)f2bf(vv[3]) << 16);
        o.z = (unsigned)f2bf(vv[4]) | ((unsigned)f2bf(vv[5]) << 16);
        o.w = (unsigned)f2bf(vv[6]) | ((unsigned)f2bf(vv[7]) << 16);
        *(uint4*)op = o;
        o.x = (unsigned)f2bf(vv[8])  | ((unsigned)f2bf(vv[9]) << 16);
        o.y = (unsigned)f2bf(vv[10]) | ((unsigned)f2bf(vv[11]) << 16);
        o.z = (unsigned)f2bf(vv[12]) | ((unsigned)f2bf(vv[13]) << 16);
        o.w = (unsigned)f2bf(vv[14]) | ((unsigned)f2bf(vv[15]) << 16);
        *(uint4*)(op + 64) = o;
    }
}

// =====================================================================
__global__ __launch_bounds__(256) void k_gather(const int* __restrict__ head,
                                                const int* __restrict__ rel,
                                                const float* __restrict__ ent,
                                                const float* __restrict__ rele,
                                                float* __restrict__ out) {
    int t = blockIdx.x * 256 + threadIdx.x;
    int row = t >> 5, sg = t & 31;
    int hh = head[row], rr = rel[row];
    float4 a = ((const float4*)(ent + (size_t)hh * 128))[sg];
    float4 b = ((const float4*)(rele + (size_t)rr * 128))[sg];
    float4 o;
    o.x = a.x + b.x; o.y = a.y + b.y; o.z = a.z + b.z; o.w = a.w + b.w;
    ((float4*)(out + (size_t)row * 128))[sg] = o;
}

// =====================================================================
extern "C" void kernel_launch(void* const* d_in, const int* in_sizes, int n_in,
                              void* d_out, int out_size, void* d_ws, size_t ws_size,
                              hipStream_t stream) {
    const int*   head = (const int*)d_in[0];
    const int*   rel  = (const int*)d_in[1];
    const float* adj  = (const float*)d_in[2];
    const float* ent  = (const float*)d_in[3];
    const float* rele = (const float*)d_in[4];
    const float* W0   = (const float*)d_in[5];
    const float* a0   = (const float*)d_in[6];
    const float* Wm   = (const float*)d_in[7];
    const float* am   = (const float*)d_in[8];
    const float* Wo   = (const float*)d_in[9];
    const float* ao   = (const float*)d_in[10];

    char* ws = (char*)d_ws;
    unsigned* mask = (unsigned*)(ws + 0);                 // 2 MB
    u16* WT0 = (u16*)(ws + 2097152);                      // 128 KB
    u16* WT5 = (u16*)(ws + 2228224);                      // 4.625 MB
    u16* WhT = (u16*)(ws + 7077888);                      // 4 MB (f16)
    float* f1 = (float*)(ws + 11272192);                  // 64 KB
    u16* xA = (u16*)(ws + 11403264);                      // 4 MB
    u16* xB = (u16*)(ws + 15597568);                      // 4 MB
    u16* x0 = (u16*)(ws + 19791872);                      // 1 MB
    float* E12 = (float*)(ws + 20840448);                 // 128 KB
    int* slots = (int*)(ws + 20971520);                   // 44 ints (f2-max per layer/head)

    float* out_x = (float*)d_out;
    float* out_comb = out_x + (size_t)4096 * 128;

    k_mask<<<2048, 256, 0, stream>>>(adj, mask, slots);
    k_cvt<<<512, 256, 0, stream>>>(ent, x0);
    k_trans<<<dim3(4, 4, 4), dim3(32, 8), 0, stream>>>(W0, WT0, 128);
    k_trans<<<dim3(16, 4, 36), dim3(32, 8), 0, stream>>>(Wm, WT5, 512);
    k_trans<<<dim3(16, 4, 1), dim3(32, 8), 0, stream>>>(Wo, WT5 + (size_t)36 * 512 * 128, 512);
    k_gather<<<512, 256, 0, stream>>>(head, rel, ent, rele, out_comb);

    // layer 0 : D -> H*D   (slot 0)
    k_proj<<<dim3(64, 4), 1024, 0, stream>>>(x0, WT0, a0, WhT, f1, E12, slots, 128);
    k_attn<false><<<dim3(64, 4), 512, 0, stream>>>(WhT, f1, E12, (const unsigned char*)mask,
                                                   slots, xA, 512);
    u16 *xc = xA, *xn = xB;
    // 9 middle layers : slots 1..9
    for (int l = 0; l < 9; l++) {
        k_proj<<<dim3(64, 4), 1024, 0, stream>>>(xc, WT5 + (size_t)l * 4 * 512 * 128,
                                                 am + (size_t)l * 4 * 256, WhT, f1, E12,
                                                 slots + (l + 1) * 4, 512);
        k_attn<false><<<dim3(64, 4), 512, 0, stream>>>(WhT, f1, E12, (const unsigned char*)mask,
                                                       slots + (l + 1) * 4, xn, 512);
        u16* t = xc; xc = xn; xn = t;
    }
    // output layer : slot 10
    k_proj<<<dim3(64, 1), 1024, 0, stream>>>(xc, WT5 + (size_t)36 * 512 * 128, ao, WhT, f1, E12,
                                             slots + 40, 512);
    k_attn<true><<<dim3(64, 1), 512, 0, stream>>>(WhT, f1, E12, (const unsigned char*)mask,
                                                  slots + 40, out_x, 128);
}

// Round 6
// 1188.792 us; speedup vs baseline: 1.0915x; 1.0915x over previous
//
#include <hip/hip_runtime.h>
#include <hip/hip_fp16.h>

typedef unsigned short u16;
typedef short bf16x8 __attribute__((ext_vector_type(8)));
typedef _Float16 half8 __attribute__((ext_vector_type(8)));
typedef float f32x4 __attribute__((ext_vector_type(4)));

__device__ __forceinline__ u16 f2bf(float f) {
    unsigned u = __float_as_uint(f);
    return (u16)((u + 0x7fffu + ((u >> 16) & 1u)) >> 16);
}
__device__ __forceinline__ u16 f2h(float f) {
    __half h = __float2half_rn(f);
    return *reinterpret_cast<u16*>(&h);
}

// ---- async global->LDS, width 16B per lane, dest = wave base + lane*16 ----
__device__ __forceinline__ void gload_lds16(const void* g, void* l) {
    __builtin_amdgcn_global_load_lds(
        (const __attribute__((address_space(1))) unsigned int*)g,
        (__attribute__((address_space(3))) unsigned int*)l, 16, 0, 0);
}

// =====================================================================
// Bitmask + init of the per-layer f2-max atomic slots
__global__ __launch_bounds__(256) void k_mask(const float* __restrict__ adj,
                                              unsigned* __restrict__ mask,
                                              int* __restrict__ slots) {
    int w = blockIdx.x * 256 + threadIdx.x;
    const float4* q = (const float4*)(adj + (size_t)w * 32);
    unsigned bits = 0u;
#pragma unroll
    for (int i = 0; i < 8; i++) {
        float4 v = q[i];
        if (v.x > 0.f) bits |= (1u << (i * 4 + 0));
        if (v.y > 0.f) bits |= (1u << (i * 4 + 1));
        if (v.z > 0.f) bits |= (1u << (i * 4 + 2));
        if (v.w > 0.f) bits |= (1u << (i * 4 + 3));
    }
    mask[w] = bits;
    if (blockIdx.x == 0 && threadIdx.x < 64) slots[threadIdx.x] = (int)0x80000000;
}

// =====================================================================
__global__ void k_trans(const float* __restrict__ in, u16* __restrict__ out, int K) {
    __shared__ float t[32][33];
    const float* src = in + (size_t)blockIdx.z * K * 128;
    u16* dst = out + (size_t)blockIdx.z * K * 128;
    int k0 = blockIdx.x * 32, n0 = blockIdx.y * 32;
    int tx = threadIdx.x, ty = threadIdx.y;
#pragma unroll
    for (int i = 0; i < 32; i += 8) t[ty + i][tx] = src[(size_t)(k0 + ty + i) * 128 + n0 + tx];
    __syncthreads();
#pragma unroll
    for (int i = 0; i < 32; i += 8) dst[(size_t)(n0 + ty + i) * K + k0 + tx] = f2bf(t[tx][ty + i]);
}

// =====================================================================
__global__ __launch_bounds__(256) void k_cvt(const float* __restrict__ in,
                                             u16* __restrict__ out) {
    int t = blockIdx.x * 256 + threadIdx.x;
    float4 v = ((const float4*)in)[t];
    uint2 o;
    o.x = (unsigned)f2bf(v.x) | ((unsigned)f2bf(v.y) << 16);
    o.y = (unsigned)f2bf(v.z) | ((unsigned)f2bf(v.w) << 16);
    ((uint2*)out)[t] = o;
}

// =====================================================================
// Projection. X bf16, WT bf16 [n][k]. Writes WhT[n][j] as F16, f1 fp32,
// E12 = {2^f2', 2^0.2f2'} fp32, and atomicMax of f2' into fsl[h].
__global__ __launch_bounds__(1024, 4) void k_proj(const u16* __restrict__ X,
                                                  const u16* __restrict__ WT,
                                                  const float* __restrict__ avec,
                                                  u16* __restrict__ WhT,
                                                  float* __restrict__ f1,
                                                  float* __restrict__ E12g,
                                                  int* __restrict__ fsl, int Fin) {
    __shared__ u16 As[2][64 * 32];
    __shared__ u16 Bs[2][128 * 32];
    __shared__ float fpart[4][64][2];
    const int tid = threadIdx.x;
    const int wv = tid >> 6, lane = tid & 63;
    const int rg = wv & 3, cg = wv >> 2;
    const int c = lane & 15, quad = lane >> 4;
    const int bofs = (quad ^ ((c >> 1) & 3)) * 8;
    const int h = blockIdx.y;
    const int j0 = blockIdx.x * 64;
    const u16* Wp = WT + (size_t)h * 128 * Fin;
    const int sgr = ((lane & 3) ^ ((lane >> 3) & 3)) * 8;

#define PROJ_STAGE(buf, kb)                                                              \
    do {                                                                                 \
        if (cg == 0)                                                                     \
            gload_lds16(X + (size_t)(j0 + rg * 16 + (lane >> 2)) * Fin + (kb) + sgr,     \
                        (void*)&As[buf][rg * 16 * 32]);                                  \
        else if (cg <= 2)                                                                \
            gload_lds16(Wp + (size_t)((cg - 1) * 64 + rg * 16 + (lane >> 2)) * Fin + (kb) + sgr, \
                        (void*)&Bs[buf][((cg - 1) * 64 + rg * 16) * 32]);                \
    } while (0)

    PROJ_STAGE(0, 0);
    __syncthreads();

    f32x4 acc[2];
    acc[0] = (f32x4){0.f, 0.f, 0.f, 0.f};
    acc[1] = (f32x4){0.f, 0.f, 0.f, 0.f};

    int it = 0;
    for (int kb = 0; kb < Fin; kb += 32, it++) {
        const int cur = it & 1;
        if (kb + 32 < Fin) PROJ_STAGE(cur ^ 1, kb + 32);
        bf16x8 av = *(const bf16x8*)&As[cur][(rg * 16 + c) * 32 + bofs];
#pragma unroll
        for (int e = 0; e < 2; e++) {
            bf16x8 bv = *(const bf16x8*)&Bs[cur][((cg * 2 + e) * 16 + c) * 32 + bofs];
            acc[e] = __builtin_amdgcn_mfma_f32_16x16x32_bf16(av, bv, acc[e], 0, 0, 0);
        }
        __syncthreads();
    }

    u16* Wo = WhT + (size_t)h * 128 * 4096;
    const float* ah = avec + h * 256;
    float p1[4] = {0, 0, 0, 0}, p2[4] = {0, 0, 0, 0};
#pragma unroll
    for (int e = 0; e < 2; e++) {
        const int n = (cg * 2 + e) * 16 + c;
        float a1 = ah[n];
        float a2 = ah[128 + n];
        u16 w4[4];
#pragma unroll
        for (int r = 0; r < 4; r++) {
            float v = acc[e][r];
            w4[r] = f2h(v);                      // f16 output
            p1[r] += v * a1;
            p2[r] += v * a2;
        }
        uint2 pk;
        pk.x = (unsigned)w4[0] | ((unsigned)w4[1] << 16);
        pk.y = (unsigned)w4[2] | ((unsigned)w4[3] << 16);
        *(uint2*)&Wo[(size_t)n * 4096 + j0 + rg * 16 + quad * 4] = pk;
    }
#pragma unroll
    for (int off = 1; off < 16; off <<= 1) {
#pragma unroll
        for (int r = 0; r < 4; r++) {
            p1[r] += __shfl_xor(p1[r], off);
            p2[r] += __shfl_xor(p2[r], off);
        }
    }
    if (c == 0) {
#pragma unroll
        for (int r = 0; r < 4; r++) {
            fpart[cg][rg * 16 + quad * 4 + r][0] = p1[r];
            fpart[cg][rg * 16 + quad * 4 + r][1] = p2[r];
        }
    }
    __syncthreads();
    if (tid < 64) {
        float s1 = fpart[0][tid][0] + fpart[1][tid][0] + fpart[2][tid][0] + fpart[3][tid][0];
        float s2 = fpart[0][tid][1] + fpart[1][tid][1] + fpart[2][tid][1] + fpart[3][tid][1];
        f1[h * 4096 + j0 + tid] = s1;
        const float LOG2E = 1.4426950408889634f;
        float d = s2 * LOG2E;
        float* e12 = E12g + h * 8192 + 2 * (j0 + tid);
        e12[0] = __builtin_amdgcn_exp2f(d);
        e12[1] = __builtin_amdgcn_exp2f(0.2f * d);
        float dm = d;
#pragma unroll
        for (int off = 1; off < 64; off <<= 1) dm = fmaxf(dm, __shfl_xor(dm, off));
        if (tid == 0) {
            int b = __float_as_int(dm);
            atomicMax(fsl + h, b >= 0 ? b : (b ^ 0x7fffffff));
        }
    }
}

// =====================================================================
// Fused masked softmax attention + ELU.
// 1024 thr = 16 waves = 8 j-groups (512 j each) x 2 row-groups, TWO 16-row
// A-fragments per wave (F=2): every Bs ds_read_b128 feeds 2 MFMAs, halving
// per-CU LDS traffic vs r0 while KEEPING 16 waves of TLP.
//  - f16 everywhere: WhT f16, P = max(C1*E1, C2*E2) in packed f16
//    (leakyrelu-exp select == max in the 2^ domain; r5-proven numerics)
//  - E-tables in LDS (16 KB), filled once; no global loads in the k-loop
//    except tiny per-4-step mask uint4s (drained with the stage DMA)
//  - ones-MFMA row denominators (fp32-exact over the same f16 P)
//  - Bs XOR-swizzle; double-buffered; one barrier per k-step (16 steps)
template <bool F32OUT>
__global__ __launch_bounds__(1024, 4) void k_attn(const u16* __restrict__ WhT,
                                                  const float* __restrict__ f1g,
                                                  const float* __restrict__ E12g,
                                                  const unsigned char* __restrict__ maskb,
                                                  const int* __restrict__ fmx,
                                                  void* __restrict__ outp, int ostride) {
    // SM layout: Bs [8 jg][2 buf][128n*32j] f16 = 128 KB | EL 16 KB | lpart 2 KB
    // After k-loop, first 135168 B (Bs+EL, both dead) reused as 4 Q-buffers.
    __shared__ uint4 SMv[9344];            // 149504 B
    char* SM = (char*)SMv;
    u16* Bsb = (u16*)SM;
    unsigned* EL = (unsigned*)(SM + 131072);
    float* lpart = (float*)(SM + 147456);  // [8][64]

    const int tid = threadIdx.x;
    const int wv = tid >> 6, lane = tid & 63;
    const int jg = wv >> 1, rg = wv & 1;
    const int c = lane & 15, quad = lane >> 4;
    const int bofs = (quad ^ ((c >> 1) & 3)) * 8;          // swizzled read granule
    const int sgr = ((lane & 3) ^ ((lane >> 3) & 3)) * 8;  // swizzled source granule
    const int h = blockIdx.y;
    const int i0 = blockIdx.x * 64;
    const float LOG2E = 1.4426950408889634f;
    const u16* Wp = WhT + (size_t)h * 128 * 4096;

    u16* tile0 = Bsb + (jg * 2 + 0) * 4096;
    u16* tile1 = Bsb + (jg * 2 + 1) * 4096;

    // stage tile (kb) of this jg into tbuf: 2 rg-waves x 4 gloads (64 n-rows each)
#define ATTN_STAGE(tbuf, kb)                                                             \
    do {                                                                                 \
        const int jb_ = jg * 512 + (kb) * 32;                                            \
        _Pragma("unroll")                                                                \
        for (int e_ = 0; e_ < 4; e_++)                                                   \
            gload_lds16(Wp + (size_t)(rg * 64 + e_ * 16 + (lane >> 2)) * 4096 + jb_ + sgr, \
                        (void*)((tbuf) + (rg * 64 + e_ * 16) * 32));                     \
    } while (0)

    ATTN_STAGE(tile0, 0);

    // ---- F2MAX + EL fill (4 j per thread) ----
    int fk = fmx[h];
    float F2MAX = __int_as_float(fk >= 0 ? fk : (fk ^ 0x7fffffff));
    float t1 = __builtin_amdgcn_exp2f(-F2MAX);
    float t2 = __builtin_amdgcn_exp2f(-0.2f * F2MAX);
    {
        int j = tid * 4;
        const float4* eg = (const float4*)(E12g + h * 8192 + 2 * j);
        float4 v0 = eg[0], v1 = eg[1];
        __half2 a0 = __floats2half2_rn(v0.x * t1, v0.y * t2);
        __half2 a1 = __floats2half2_rn(v0.z * t1, v0.w * t2);
        __half2 a2 = __floats2half2_rn(v1.x * t1, v1.y * t2);
        __half2 a3 = __floats2half2_rn(v1.z * t1, v1.w * t2);
        uint4 pk;
        pk.x = *(unsigned*)&a0; pk.y = *(unsigned*)&a1;
        pk.z = *(unsigned*)&a2; pk.w = *(unsigned*)&a3;
        *(uint4*)&EL[j] = pk;
    }

    // ---- per-frag constants {C1,C2} f16x2 (rows rg*32+c and rg*32+16+c) ----
    __half2 cpa, cpb;
    {
        float rf1 = f1g[h * 4096 + i0 + rg * 32 + c] * LOG2E;
        float zb = rf1 + F2MAX, rm = fmaxf(zb, 0.2f * zb);
        cpa = __floats2half2_rn(__builtin_amdgcn_exp2f(zb - rm),
                                __builtin_amdgcn_exp2f(0.2f * zb - rm));
    }
    {
        float rf1 = f1g[h * 4096 + i0 + rg * 32 + 16 + c] * LOG2E;
        float zb = rf1 + F2MAX, rm = fmaxf(zb, 0.2f * zb);
        cpb = __floats2half2_rn(__builtin_amdgcn_exp2f(zb - rm),
                                __builtin_amdgcn_exp2f(0.2f * zb - rm));
    }

    // mask row base pointers (64-byte span per row over this jg's 512 j)
    const unsigned char* mpa = maskb + (size_t)(i0 + rg * 32 + c) * 512 + jg * 64;
    const unsigned char* mpb = mpa + 16 * 512;

    half8 ones;
#pragma unroll
    for (int i = 0; i < 8; i++) ones[i] = (_Float16)1.0f;

    f32x4 accA[8], accB[8];
#pragma unroll
    for (int i = 0; i < 8; i++) {
        accA[i] = (f32x4){0.f, 0.f, 0.f, 0.f};
        accB[i] = (f32x4){0.f, 0.f, 0.f, 0.f};
    }
    f32x4 alA = (f32x4){0.f, 0.f, 0.f, 0.f};
    f32x4 alB = (f32x4){0.f, 0.f, 0.f, 0.f};

    union AF { half8 v; unsigned u[4]; };

#define COMPF(dst, mbv, cpf)                                                             \
    do {                                                                                 \
        _Pragma("unroll")                                                                \
        for (int t = 0; t < 4; t++) {                                                    \
            __half2 e0 = *(const __half2*)&ed[2 * t];                                    \
            __half2 e1 = *(const __half2*)&ed[2 * t + 1];                                \
            __half2 pr0 = __hmul2(e0, (cpf));                                            \
            __half2 pr1 = __hmul2(e1, (cpf));                                            \
            __half m0 = __hmax(__low2half(pr0), __high2half(pr0));                       \
            __half m1 = __hmax(__low2half(pr1), __high2half(pr1));                       \
            __half2 pk2 = __halves2half2(m0, m1);                                        \
            unsigned msk = ((((mbv) >> (2 * t)) & 1u) ? 0xffffu : 0u) |                  \
                           ((((mbv) >> (2 * t + 1)) & 1u) ? 0xffff0000u : 0u);           \
            dst.u[t] = (*(const unsigned*)&pk2) & msk;                                   \
        }                                                                                \
    } while (0)

#define STEP(kb, PAR, mwa, mwb)                                                          \
    do {                                                                                 \
        u16* curb = (PAR) ? tile1 : tile0;                                               \
        if ((kb) < 15) ATTN_STAGE((PAR) ? tile0 : tile1, (kb) + 1);                      \
        uint4 ew0 = *(const uint4*)&EL[jg * 512 + (kb) * 32 + quad * 8];                 \
        uint4 ew1 = *(const uint4*)&EL[jg * 512 + (kb) * 32 + quad * 8 + 4];             \
        const unsigned ed[8] = {ew0.x, ew0.y, ew0.z, ew0.w, ew1.x, ew1.y, ew1.z, ew1.w}; \
        const unsigned mbva = ((mwa) >> (8 * quad)) & 0xffu;                             \
        const unsigned mbvb = ((mwb) >> (8 * quad)) & 0xffu;                             \
        AF afa, afb;                                                                     \
        COMPF(afa, mbva, cpa);                                                           \
        COMPF(afb, mbvb, cpb);                                                           \
        _Pragma("unroll")                                                                \
        for (int nt = 0; nt < 8; nt++) {                                                 \
            half8 bv = *(const half8*)&curb[(nt * 16 + c) * 32 + bofs];                  \
            accA[nt] = __builtin_amdgcn_mfma_f32_16x16x32_f16(afa.v, bv, accA[nt], 0, 0, 0); \
            accB[nt] = __builtin_amdgcn_mfma_f32_16x16x32_f16(afb.v, bv, accB[nt], 0, 0, 0); \
        }                                                                                \
        alA = __builtin_amdgcn_mfma_f32_16x16x32_f16(afa.v, ones, alA, 0, 0, 0);         \
        alB = __builtin_amdgcn_mfma_f32_16x16x32_f16(afb.v, ones, alB, 0, 0, 0);         \
        __syncthreads();                                                                 \
    } while (0)

    __syncthreads();               // EL visible + tile0 staged (barrier drains vmcnt)

    for (int s = 0; s < 4; s++) {
        uint4 mca = *(const uint4*)(mpa + 16 * s);
        uint4 mcb = *(const uint4*)(mpb + 16 * s);
        STEP(s * 4 + 0, 0, mca.x, mcb.x);
        STEP(s * 4 + 1, 1, mca.y, mcb.y);
        STEP(s * 4 + 2, 0, mca.z, mcb.z);
        STEP(s * 4 + 3, 1, mca.w, mcb.w);
    }

    // ---- row denominators from ones-MFMA ----
    if (c == 0) {
#pragma unroll
        for (int r = 0; r < 4; r++) {
            lpart[jg * 64 + rg * 32 + quad * 4 + r] = alA[r];
            lpart[jg * 64 + rg * 32 + 16 + quad * 4 + r] = alB[r];
        }
    }
    __syncthreads();               // everyone done with Bs/EL

    // ---- cross-jg reduction: 4 quarter-buffers Q[q] = [64][132] over Bs+EL ----
    float* Q = (float*)SM;
#define QIDX(f, ntv, rv) ((rg * 32 + (f) * 16 + quad * 4 + (rv)) * 132 + (ntv) * 16 + c)
    if (jg >= 4) {
        float* rq = Q + (jg - 4) * 8448;
#pragma unroll
        for (int nt = 0; nt < 8; nt++)
#pragma unroll
            for (int r = 0; r < 4; r++) {
                rq[QIDX(0, nt, r)] = accA[nt][r];
                rq[QIDX(1, nt, r)] = accB[nt][r];
            }
    }
    __syncthreads();
    if (jg < 4) {
        float* rq = Q + jg * 8448;
#pragma unroll
        for (int nt = 0; nt < 8; nt++)
#pragma unroll
            for (int r = 0; r < 4; r++) {
                rq[QIDX(0, nt, r)] += accA[nt][r];
                rq[QIDX(1, nt, r)] += accB[nt][r];
            }
    }
    __syncthreads();
    {
        f32x4* q0 = (f32x4*)Q;
        f32x4* q1 = (f32x4*)(Q + 8448);
        f32x4* q2 = (f32x4*)(Q + 16896);
        f32x4* q3 = (f32x4*)(Q + 25344);
        for (int t = tid; t < 2112; t += 1024) { q0[t] += q2[t]; q1[t] += q3[t]; }
    }
    __syncthreads();

    // ---- epilogue: row = tid>>4, col-octet = tid&15 ----
    const int row = tid >> 4, cb = tid & 15;
    float l = 0.f;
#pragma unroll
    for (int g = 0; g < 8; g++) l += lpart[g * 64 + row];
    const float linv = 1.0f / l;
    float vv[8];
#pragma unroll
    for (int t = 0; t < 8; t++) {
        int idx = row * 132 + cb * 8 + t;
        float v = (Q[idx] + Q[8448 + idx]) * linv;
        vv[t] = v > 0.f ? v : __expf(v) - 1.f;       // ELU
    }
    const size_t obase = (size_t)(i0 + row) * ostride + h * 128 + cb * 8;
    if (F32OUT) {
        float* op = (float*)outp + obase;
        *(float4*)op = *(float4*)&vv[0];
        *(float4*)(op + 4) = *(float4*)&vv[4];
    } else {
        uint4 o;
        o.x = (unsigned)f2bf(vv[0]) | ((unsigned)f2bf(vv[1]) << 16);
        o.y = (unsigned)f2bf(vv[2]) | ((unsigned)f2bf(vv[3]) << 16);
        o.z = (unsigned)f2bf(vv[4]) | ((unsigned)f2bf(vv[5]) << 16);
        o.w = (unsigned)f2bf(vv[6]) | ((unsigned)f2bf(vv[7]) << 16);
        *(uint4*)((u16*)outp + obase) = o;
    }
}

// =====================================================================
__global__ __launch_bounds__(256) void k_gather(const int* __restrict__ head,
                                                const int* __restrict__ rel,
                                                const float* __restrict__ ent,
                                                const float* __restrict__ rele,
                                                float* __restrict__ out) {
    int t = blockIdx.x * 256 + threadIdx.x;
    int row = t >> 5, sg = t & 31;
    int hh = head[row], rr = rel[row];
    float4 a = ((const float4*)(ent + (size_t)hh * 128))[sg];
    float4 b = ((const float4*)(rele + (size_t)rr * 128))[sg];
    float4 o;
    o.x = a.x + b.x; o.y = a.y + b.y; o.z = a.z + b.z; o.w = a.w + b.w;
    ((float4*)(out + (size_t)row * 128))[sg] = o;
}

// =====================================================================
extern "C" void kernel_launch(void* const* d_in, const int* in_sizes, int n_in,
                              void* d_out, int out_size, void* d_ws, size_t ws_size,
                              hipStream_t stream) {
    const int*   head = (const int*)d_in[0];
    const int*   rel  = (const int*)d_in[1];
    const float* adj  = (const float*)d_in[2];
    const float* ent  = (const float*)d_in[3];
    const float* rele = (const float*)d_in[4];
    const float* W0   = (const float*)d_in[5];
    const float* a0   = (const float*)d_in[6];
    const float* Wm   = (const float*)d_in[7];
    const float* am   = (const float*)d_in[8];
    const float* Wo   = (const float*)d_in[9];
    const float* ao   = (const float*)d_in[10];

    char* ws = (char*)d_ws;
    unsigned* mask = (unsigned*)(ws + 0);                 // 2 MB
    u16* WT0 = (u16*)(ws + 2097152);                      // 128 KB
    u16* WT5 = (u16*)(ws + 2228224);                      // 4.625 MB
    u16* WhT = (u16*)(ws + 7077888);                      // 4 MB (f16)
    float* f1 = (float*)(ws + 11272192);                  // 64 KB
    u16* xA = (u16*)(ws + 11403264);                      // 4 MB
    u16* xB = (u16*)(ws + 15597568);                      // 4 MB
    u16* x0 = (u16*)(ws + 19791872);                      // 1 MB
    float* E12 = (float*)(ws + 20840448);                 // 128 KB
    int* slots = (int*)(ws + 20971520);                   // 44 ints

    float* out_x = (float*)d_out;
    float* out_comb = out_x + (size_t)4096 * 128;

    k_mask<<<2048, 256, 0, stream>>>(adj, mask, slots);
    k_cvt<<<512, 256, 0, stream>>>(ent, x0);
    k_trans<<<dim3(4, 4, 4), dim3(32, 8), 0, stream>>>(W0, WT0, 128);
    k_trans<<<dim3(16, 4, 36), dim3(32, 8), 0, stream>>>(Wm, WT5, 512);
    k_trans<<<dim3(16, 4, 1), dim3(32, 8), 0, stream>>>(Wo, WT5 + (size_t)36 * 512 * 128, 512);
    k_gather<<<512, 256, 0, stream>>>(head, rel, ent, rele, out_comb);

    // layer 0 : D -> H*D   (slots 0..3)
    k_proj<<<dim3(64, 4), 1024, 0, stream>>>(x0, WT0, a0, WhT, f1, E12, slots, 128);
    k_attn<false><<<dim3(64, 4), 1024, 0, stream>>>(WhT, f1, E12, (const unsigned char*)mask,
                                                    slots, xA, 512);
    u16 *xc = xA, *xn = xB;
    // 9 middle layers : slots 4..39
    for (int l = 0; l < 9; l++) {
        k_proj<<<dim3(64, 4), 1024, 0, stream>>>(xc, WT5 + (size_t)l * 4 * 512 * 128,
                                                 am + (size_t)l * 4 * 256, WhT, f1, E12,
                                                 slots + (l + 1) * 4, 512);
        k_attn<false><<<dim3(64, 4), 1024, 0, stream>>>(WhT, f1, E12, (const unsigned char*)mask,
                                                        slots + (l + 1) * 4, xn, 512);
        u16* t = xc; xc = xn; xn = t;
    }
    // output layer : slot 40
    k_proj<<<dim3(64, 1), 1024, 0, stream>>>(xc, WT5 + (size_t)36 * 512 * 128, ao, WhT, f1, E12,
                                             slots + 40, 512);
    k_attn<true><<<dim3(64, 1), 1024, 0, stream>>>(WhT, f1, E12, (const unsigned char*)mask,
                                                   slots + 40, out_x, 128);
}